// Round 3
// baseline (467.539 us; speedup 1.0000x reference)
//
#include <hip/hip_runtime.h>

constexpr int B = 8, S = 2048, D = 256;
constexpr int TQ = 32;              // query rows per block (main kernel)
constexpr float SCALE = 0.0625f;    // 1/sqrt(256)
constexpr int PSTRIDE = 2056;       // 2048 + 8 bf16 pad -> 2-way bank aliasing (free)

typedef __attribute__((ext_vector_type(8))) short bf16x8;  // 8 bf16 in 4 VGPRs
typedef __attribute__((ext_vector_type(4))) float f32x4;

__device__ __forceinline__ short f2bf(float f) {
    union { float f; unsigned u; } c; c.f = f;
    unsigned u = c.u + 0x7fffu + ((c.u >> 16) & 1u);   // RNE
    return (short)(u >> 16);
}

// ---- fused pre-pass: convQ | convK | transposeV | packMask in ONE launch ----
// grid layout: [0,4096) convQ, [4096,8192) convK, [8192,9216) transposeV,
//              [9216,13312) packMask (ballot version, 4 rows per 256-thr block)
__global__ __launch_bounds__(256) void prepass(
    const float* __restrict__ q, const float* __restrict__ k,
    const float* __restrict__ v, const int* __restrict__ mask,
    short* __restrict__ qb, short* __restrict__ kb,
    short* __restrict__ vtb, unsigned short* __restrict__ pm)
{
    __shared__ float tile[64][65];
    const int blk = blockIdx.x;
    const int tid = threadIdx.x;

    if (blk < 8192) {
        // ---- conv q/k: fp32 -> bf16, float4 granularity ----
        const float* in = (blk < 4096) ? q : k;
        short* out = (blk < 4096) ? qb : kb;
        int i = (blk & 4095) * 256 + tid;
        float4 x = ((const float4*)in)[i];
        short4 o; o.x = f2bf(x.x); o.y = f2bf(x.y); o.z = f2bf(x.z); o.w = f2bf(x.w);
        ((short4*)out)[i] = o;
    } else if (blk < 9216) {
        // ---- transpose V: [B][S][D] fp32 -> [B][D][S] bf16 ----
        int blk2 = blk - 8192;
        int b = blk2 >> 7, rem = blk2 & 127;
        int d0 = (rem & 3) * 64, k0 = (rem >> 2) * 64;
        int tr = tid >> 4, tc = tid & 15;
        const float* vb = v + (size_t)b * S * D;
        #pragma unroll
        for (int r = 0; r < 4; ++r) {
            int key = r * 16 + tr;
            float4 x = *(const float4*)(vb + (size_t)(k0 + key) * D + d0 + tc * 4);
            tile[key][tc * 4 + 0] = x.x; tile[key][tc * 4 + 1] = x.y;
            tile[key][tc * 4 + 2] = x.z; tile[key][tc * 4 + 3] = x.w;
        }
        __syncthreads();
        short* vtbb = vtb + (size_t)b * D * S;
        #pragma unroll
        for (int r = 0; r < 4; ++r) {
            int d = r * 16 + tr;
            short4 o;
            o.x = f2bf(tile[tc * 4 + 0][d]); o.y = f2bf(tile[tc * 4 + 1][d]);
            o.z = f2bf(tile[tc * 4 + 2][d]); o.w = f2bf(tile[tc * 4 + 3][d]);
            *(short4*)(vtbb + (size_t)(d0 + d) * S + k0 + tc * 4) = o;
        }
    } else {
        // ---- pack mask via ballot: 64 coalesced 4B loads -> 64 bits per ballot ----
        // pm[rowlin][g][l16] bit nt = (mask[rowlin][g*256 + nt*16 + l16] != 0)
        int t2 = blk - 9216;                 // 0..4095
        int w = tid >> 6, lane = tid & 63;
        int l16 = lane & 15;
        int rowlin = t2 * 4 + w;             // b*S + row
        const int* mrow = mask + (size_t)rowlin * S;
        unsigned short* pmrow = pm + (size_t)rowlin * 128;
        #pragma unroll
        for (int g = 0; g < 8; ++g) {
            unsigned v16 = 0;
            #pragma unroll
            for (int u = 0; u < 4; ++u) {
                int col = g * 256 + u * 64 + lane;
                unsigned long long bal = __ballot(mrow[col] != 0);
                unsigned nib = (unsigned)((bal >> l16) & 1ull)
                             | (unsigned)((bal >> (l16 + 16)) & 1ull) << 1
                             | (unsigned)((bal >> (l16 + 32)) & 1ull) << 2
                             | (unsigned)((bal >> (l16 + 48)) & 1ull) << 3;
                v16 |= nib << (u * 4);
            }
            if (lane < 16) pmrow[g * 16 + l16] = (unsigned short)v16;
        }
    }
}

// ---- main fused kernel: 512 threads (8 waves), 1 block = 32 q-rows x 1 batch ----
// LDS: p_lds 32*2056*2 = 128.5 KB + red 1 KB -> 1 block/CU, 2 waves/SIMD
__global__ __launch_bounds__(512, 2) void attn_mfma(
    const short* __restrict__ qb, const short* __restrict__ kb,
    const short* __restrict__ vtb, const unsigned short* __restrict__ pmg,
    float* __restrict__ outg, float* __restrict__ attng)
{
    const int b = blockIdx.y;
    const int i0 = blockIdx.x * TQ;
    const int tid = threadIdx.x;
    const int wave = tid >> 6, lane = tid & 63;
    const int quad = lane >> 4, l16 = lane & 15;

    __shared__ short p_lds[TQ][PSTRIDE];
    __shared__ float red[8][TQ];

    // prefetch packed mask: one ushort per owned row (8 rows), consumed in phase B.
    unsigned pmv[2][4];
    {
        const unsigned short* pmb = pmg + (((size_t)b * S + i0 + quad * 4) * 8 + wave) * 16 + l16;
        #pragma unroll
        for (int mt = 0; mt < 2; ++mt)
            #pragma unroll
            for (int r = 0; r < 4; ++r)
                pmv[mt][r] = pmb[(size_t)(mt * 16 + r) * 128];
    }

    // ---------- phase A: scores = Q K^T (wave w owns keys [w*256, w*256+256)) ----------
    bf16x8 aq[2][8];
    const short* qbase = qb + ((size_t)b * S + i0) * D;
    #pragma unroll
    for (int mt = 0; mt < 2; ++mt)
        #pragma unroll
        for (int ks = 0; ks < 8; ++ks)
            aq[mt][ks] = *(const bf16x8*)(qbase + (size_t)(mt * 16 + l16) * D + ks * 32 + quad * 8);

    f32x4 acc[2][16];
    #pragma unroll
    for (int mt = 0; mt < 2; ++mt)
        #pragma unroll
        for (int nt = 0; nt < 16; ++nt)
            acc[mt][nt] = f32x4{0.f, 0.f, 0.f, 0.f};

    const short* kbase = kb + (size_t)b * S * D;
    #pragma unroll
    for (int nt = 0; nt < 16; ++nt) {
        const int n0 = wave * 256 + nt * 16;
        bf16x8 bk[8];
        #pragma unroll
        for (int ks = 0; ks < 8; ++ks)
            bk[ks] = *(const bf16x8*)(kbase + (size_t)(n0 + l16) * D + ks * 32 + quad * 8);
        #pragma unroll
        for (int ks = 0; ks < 8; ++ks) {
            acc[0][nt] = __builtin_amdgcn_mfma_f32_16x16x32_bf16(aq[0][ks], bk[ks], acc[0][nt], 0, 0, 0);
            acc[1][nt] = __builtin_amdgcn_mfma_f32_16x16x32_bf16(aq[1][ks], bk[ks], acc[1][nt], 0, 0, 0);
        }
    }

    // ---------- phase B: mask (packed bits), exp, row-sum (pure VALU, no global mem) ----------
    float rsum[2][4];
    #pragma unroll
    for (int mt = 0; mt < 2; ++mt)
        #pragma unroll
        for (int r = 0; r < 4; ++r) rsum[mt][r] = 0.f;

    #pragma unroll
    for (int mt = 0; mt < 2; ++mt) {
        #pragma unroll
        for (int nt = 0; nt < 16; ++nt) {
            #pragma unroll
            for (int r = 0; r < 4; ++r) {
                float s = acc[mt][nt][r] * SCALE;
                float sv = ((pmv[mt][r] >> nt) & 1u) ? s : -1e9f;
                float e = __expf(sv);           // exp(-1e9) underflows to 0 == reference
                acc[mt][nt][r] = e;
                rsum[mt][r] += e;
            }
        }
    }
    #pragma unroll
    for (int mt = 0; mt < 2; ++mt)
        #pragma unroll
        for (int r = 0; r < 4; ++r) {
            float v = rsum[mt][r];
            v += __shfl_xor(v, 1); v += __shfl_xor(v, 2);
            v += __shfl_xor(v, 4); v += __shfl_xor(v, 8);
            rsum[mt][r] = v;
            if (l16 == 0) red[wave][mt * 16 + quad * 4 + r] = v;
        }
    __syncthreads();

    float inv[2][4];
    #pragma unroll
    for (int mt = 0; mt < 2; ++mt)
        #pragma unroll
        for (int r = 0; r < 4; ++r) {
            float tot = 0.f;
            #pragma unroll
            for (int w = 0; w < 8; ++w) tot += red[w][mt * 16 + quad * 4 + r];
            inv[mt][r] = 1.0f / tot;
        }

    // normalize in-register, stash P (bf16) in LDS. NO global stores before the
    // barrier: the compiler's s_waitcnt vmcnt(0)-before-s_barrier would drain
    // 256 KB/block of attn stores with zero overlap. Stores go inside phase C.
    #pragma unroll
    for (int mt = 0; mt < 2; ++mt) {
        #pragma unroll
        for (int nt = 0; nt < 16; ++nt) {
            const int col = wave * 256 + nt * 16 + l16;
            #pragma unroll
            for (int r = 0; r < 4; ++r) {
                float p = acc[mt][nt][r] * inv[mt][r];
                acc[mt][nt][r] = p;             // keep normalized value for the store
                p_lds[mt * 16 + quad * 4 + r][col] = f2bf(p);
            }
        }
    }
    __syncthreads();

    // ---------- phase C: out = P V, with attn stores interleaved per chunk ----------
    f32x4 oacc[2][2];
    #pragma unroll
    for (int mt = 0; mt < 2; ++mt)
        #pragma unroll
        for (int nc = 0; nc < 2; ++nc) oacc[mt][nc] = f32x4{0.f, 0.f, 0.f, 0.f};

    const short* vbase = vtb + (size_t)b * D * S;
    const int nb = wave * 32;
    float* abase0 = attng + ((size_t)b * S + i0 + quad * 4) * S + wave * 256 + l16;

    #pragma unroll 1
    for (int kc = 0; kc < 8; ++kc) {
        #pragma unroll
        for (int k2 = 0; k2 < 8; ++k2) {
            const int ks = kc * 8 + k2;
            bf16x8 ap[2], bv[2];
            #pragma unroll
            for (int mt = 0; mt < 2; ++mt)
                ap[mt] = *(const bf16x8*)&p_lds[mt * 16 + l16][ks * 32 + quad * 8];
            #pragma unroll
            for (int nc = 0; nc < 2; ++nc)
                bv[nc] = *(const bf16x8*)(vbase + (size_t)(nb + nc * 16 + l16) * S + ks * 32 + quad * 8);
            #pragma unroll
            for (int mt = 0; mt < 2; ++mt)
                #pragma unroll
                for (int nc = 0; nc < 2; ++nc)
                    oacc[mt][nc] = __builtin_amdgcn_mfma_f32_16x16x32_bf16(ap[mt], bv[nc], oacc[mt][nc], 0, 0, 0);
        }
        // 16 of the 128 attn stores per chunk: they drain under the next chunk's
        // loads+MFMA (vmcnt retires in order; stores are newest -> don't block loads)
        #pragma unroll
        for (int j = 0; j < 16; ++j) {
            const int f = kc * 16 + j;
            const int mt = f >> 6, nt = (f >> 2) & 15, r = f & 3;
            abase0[(size_t)(mt * 16 + r) * S + nt * 16] = acc[mt][nt][r];
        }
    }

    #pragma unroll
    for (int mt = 0; mt < 2; ++mt)
        #pragma unroll
        for (int nc = 0; nc < 2; ++nc)
            #pragma unroll
            for (int r = 0; r < 4; ++r) {
                int row = i0 + mt * 16 + quad * 4 + r;
                int col = nb + nc * 16 + l16;
                outg[((size_t)b * S + row) * D + col] = oacc[mt][nc][r];
            }
}

extern "C" void kernel_launch(void* const* d_in, const int* in_sizes, int n_in,
                              void* d_out, int out_size, void* d_ws, size_t ws_size,
                              hipStream_t stream) {
    const float* q    = (const float*)d_in[0];
    const float* k    = (const float*)d_in[1];
    const float* v    = (const float*)d_in[2];
    const int*   mask = (const int*)d_in[3];
    float* out  = (float*)d_out;
    float* attn = out + (size_t)B * S * D;     // tuple order: (out, attn)

    const size_t N = (size_t)B * S * D;        // 4,194,304 elements
    short* qb  = (short*)d_ws;                 // 8 MB
    short* kb  = qb + N;                       // 8 MB
    short* vtb = kb + N;                       // 8 MB (transposed V)
    unsigned short* pm = (unsigned short*)(vtb + N);  // 4 MB packed mask

    prepass<<<dim3(13312), 256, 0, stream>>>(q, k, v, mask, qb, kb, vtb, pm);
    attn_mfma<<<dim3(S / TQ, B), 512, 0, stream>>>(qb, kb, vtb, pm, out, attn);
}